// Round 11
// baseline (145.068 us; speedup 1.0000x reference)
//
#include <hip/hip_runtime.h>

// Net_3152505995417: tiny GNN forward (N=116, E=6670, HID=64, EDIM=5).
// R12 = R11 (115.0us verified) with kC MERGED into kDEF (4 -> 3 dispatches).
// Why this fusion is safe where R3/R6's wasn't: S is rebuilt per-block in
// GATHER form (kC's exact code: wave-per-row, lane-split j, shfl tree ->
// bit-identical S), ~267KB of L2-resident G reads per block (~2us), not the
// scatter-atomic edge sweep that cost 100us. Net: -1 boundary (~4us) -1 kC
// wall (~2us) +2us redundant gather.
//  kA: nodes: X=enc@W_enc+b (LDS-staged weights), Y1=X@W1; edges: 1 thr/edge
//      d1 + G row.                                    [R11-verified verbatim]
//  kB: x2=relu(D1@Y1+b1) (LDS-staged), dv=x2.pe; W2 deferred to F.
//                                                     [R11-verified verbatim]
//  kCDEF: stage x2+dv -> S gather in LDS (kC verbatim per row) -> d2 own 4
//      rows -> Z=D2@x2 -> pool -> last block: pooled=(P/N)@W2+b2, @Wl+bl.
// LDS staging kept hot (R10 lesson: destaging = dependent L2-latency chains).

#define NN   116
#define EE   6670
#define HID  64
#define EDIM 5
#define OUTD 4
#define ENC  122
#define EPSF 1e-10f
#define NH   (NN*HID)   // 7424

__device__ __forceinline__ int eid_ij(int i, int j) {
    int a = i < j ? i : j;
    int b = i < j ? j : i;
    return a*NN - ((a*(a+1)) >> 1) + (b - a - 1);   // triu k=1 row-major
}

// kA: node blocks (0..28): X row = enc@W_enc+b_enc (LDS-staged weights),
//     Y1 row = Xrow@W1. Edge blocks (29..55): one thread per edge: d1 + G row.
__global__ __launch_bounds__(256) void kA(
    const float* __restrict__ enc, const float* __restrict__ ea,
    const float* __restrict__ W_enc, const float* __restrict__ b_enc,
    const float* __restrict__ p1, const float* __restrict__ We,
    const float* __restrict__ W1,
    float* __restrict__ Y1, float* __restrict__ d1, float* __restrict__ G)
{
    const int tid = threadIdx.x;
    if (blockIdx.x < 29) {
        __shared__ __align__(16) float sWe[ENC*HID];   // 31232 B
        __shared__ __align__(16) float sW1[HID*HID];   // 16384 B
        __shared__ __align__(16) float sEnc[4*ENC];    //  1952 B
        __shared__ float sX[4*HID];
        {
            const float4* g4 = (const float4*)W_enc; float4* s4 = (float4*)sWe;
            for (int u = tid; u < ENC*HID/4; u += 256) s4[u] = g4[u];
        }
        {
            const float4* g4 = (const float4*)W1; float4* s4 = (float4*)sW1;
            for (int u = tid; u < HID*HID/4; u += 256) s4[u] = g4[u];
        }
        {
            const float4* g4 = (const float4*)(enc + blockIdx.x*4*ENC); // 1952B-aligned
            float4* s4 = (float4*)sEnc;
            for (int u = tid; u < 4*ENC/4; u += 256) s4[u] = g4[u];
        }
        __syncthreads();
        const int w = tid >> 6, h = tid & 63;
        const int i = blockIdx.x*4 + w;
        float acc = b_enc[h];
        const float* er = sEnc + w*ENC;
        #pragma unroll 4
        for (int k = 0; k < ENC; ++k) acc = fmaf(er[k], sWe[k*HID + h], acc);
        sX[w*HID + h] = acc;
        __syncthreads();
        float a2 = 0.f;
        const float* xr = sX + w*HID;
        #pragma unroll 8
        for (int k = 0; k < HID; ++k) a2 = fmaf(xr[k], sW1[k*HID + h], a2);
        Y1[i*HID + h] = a2;
    } else {
        const int e = (blockIdx.x - 29)*256 + tid;
        if (e < EE) {
            const float* r = ea + e*EDIM;
            float rv[EDIM];
            #pragma unroll
            for (int m = 0; m < EDIM; ++m) rv[m] = r[m];
            float a0 = 0.f;
            #pragma unroll
            for (int k = 0; k < EDIM; ++k) a0 = fmaf(rv[k], p1[k], a0);
            d1[e] = a0;
            #pragma unroll
            for (int k = 0; k < EDIM; ++k) {
                float g = 0.f;
                #pragma unroll
                for (int m = 0; m < EDIM; ++m) g = fmaf(fmaxf(rv[m], 0.f), We[m*EDIM + k], g);
                G[e*EDIM + k] = g;
            }
        }
    }
}

// kB: x2 row = relu(D1@Y1 + b1) (LDS-staged); dv[i] = x2row.pe; write x2.
//     Block 0 zeroes P and cnt.
__global__ __launch_bounds__(256) void kB(
    const float* __restrict__ d1, const float* __restrict__ Y1,
    const float* __restrict__ b1, const float* __restrict__ pe,
    float* __restrict__ dv, float* __restrict__ x2,
    float* __restrict__ P, int* __restrict__ cnt)
{
    __shared__ __align__(16) float sY[NH];   // 29696 B
    __shared__ __align__(16) float sD[EE];   // 26680 B
    const int tid = threadIdx.x;
    if (blockIdx.x == 0) {
        if (tid < HID) P[tid] = 0.f;
        if (tid == 0) *cnt = 0;
    }
    {
        const float4* g4 = (const float4*)Y1; float4* s4 = (float4*)sY;
        for (int u = tid; u < NH/4; u += 256) s4[u] = g4[u];
        const float2* g2 = (const float2*)d1; float2* s2 = (float2*)sD;
        for (int u = tid; u < EE/2; u += 256) s2[u] = g2[u];
    }
    __syncthreads();
    const int w = tid >> 6, h = tid & 63;
    const int i = blockIdx.x*4 + w;
    float acc = b1[h];
    #pragma unroll 4
    for (int j = 0; j < NN; ++j) {
        int jj = (j == i) ? (j ^ 1) : j;
        float wgt = (j == i) ? 0.f : sD[eid_ij(i, jj)];
        acc = fmaf(wgt, sY[jj*HID + h], acc);
    }
    float v = fmaxf(acc, 0.f);
    float r = v * pe[h];
    #pragma unroll
    for (int off = 32; off > 0; off >>= 1) r += __shfl_down(r, off, 64);
    if (h == 0) dv[i] = r;
    x2[i*HID + h] = v;
}

// kCDEF: per block (29 blocks, 4 output rows each):
//   stage x2 + dv; rebuild full S in LDS via kC's GATHER (wave-per-row,
//   4 waves x 29 rows, bit-identical per row); d2 own 4 rows; Z = D2@x2;
//   pool -> atomicAdd P; last block: pooled=(P/N)@W2+b2, out=pooled@Wl+bl.
__global__ __launch_bounds__(256) void kCDEF(
    const float* __restrict__ G, const float* __restrict__ dvg,
    const float* __restrict__ x2,
    const float* __restrict__ be, const float* __restrict__ p2,
    const float* __restrict__ W2, const float* __restrict__ b2,
    const float* __restrict__ Wl, const float* __restrict__ bl,
    float* __restrict__ P, int* __restrict__ cnt, float* __restrict__ out)
{
    __shared__ __align__(16) float sY[NH];     // x2 tile, 29696 B
    __shared__ float sS[NN*EDIM];
    __shared__ float sDv[NN];
    __shared__ float sD2[4*NN];
    __shared__ float sR[4*HID];
    __shared__ int sLast;
    const int tid = threadIdx.x;
    const int wid = tid >> 6, lane = tid & 63;

    float ber[EDIM], p2r[EDIM];
    #pragma unroll
    for (int k = 0; k < EDIM; ++k) { ber[k] = be[k]; p2r[k] = p2[k]; }

    {
        const float4* g4 = (const float4*)x2; float4* s4 = (float4*)sY;
        for (int u = tid; u < NH/4; u += 256) s4[u] = g4[u];
    }
    if (tid < NN) sDv[tid] = dvg[tid];
    __syncthreads();

    // ---- C: S gather, kC verbatim per row; wave w owns rows w*29..w*29+28 ----
    for (int r = 0; r < 29; ++r) {
        const int i = wid*29 + r;                       // 4*29 = 116 exactly
        const float di = sDv[i];
        float acc[EDIM] = {0.f, 0.f, 0.f, 0.f, 0.f};
        #pragma unroll
        for (int rep = 0; rep < 2; ++rep) {
            const int j = lane + rep*64;
            if (j < NN && j != i) {
                const float cm = fmaxf(fmaxf(di, sDv[j]), 0.f) + EPSF;
                const float* gr = G + eid_ij(i, j)*EDIM;
                #pragma unroll
                for (int k = 0; k < EDIM; ++k) acc[k] += gr[k] / cm;
            }
        }
        #pragma unroll
        for (int k = 0; k < EDIM; ++k) {
            #pragma unroll
            for (int off = 32; off > 0; off >>= 1) acc[k] += __shfl_down(acc[k], off, 64);
        }
        if (lane == 0) {
            #pragma unroll
            for (int k = 0; k < EDIM; ++k) sS[i*EDIM + k] = acc[k];
        }
    }
    __syncthreads();

    // ---- D: d2 for the block's own 4 rows (460 edges, G direct) ----
    {
        const int i = blockIdx.x*4 + wid;
        #pragma unroll
        for (int rep = 0; rep < 2; ++rep) {
            const int j = lane + rep*64;
            if (j < NN) {
                float val = 0.f;
                if (j != i) {
                    const int a = i < j ? i : j, b = i < j ? j : i;
                    const int e = a*NN - ((a*(a+1)) >> 1) + (b - a - 1);
                    const float da = sDv[a], db = sDv[b];
                    const float rc = 1.f / (fmaxf(fmaxf(da, db), 0.f) + EPSF);
                    #pragma unroll
                    for (int k = 0; k < EDIM; ++k) {
                        const float gp = G[e*EDIM + k] * rc;
                        const float v = fmaf(da, sS[a*EDIM + k] - gp,
                                       fmaf(db, sS[b*EDIM + k] - gp, ber[k]));
                        val = fmaf(fmaxf(v, 0.f), p2r[k], val);
                    }
                }
                sD2[wid*NN + j] = val;
            }
        }
    }
    __syncthreads();

    // ---- E: Z row = D2@x2 (b2 deferred to F), partial pool ----
    {
        float acc = 0.f;
        const float* d2r = sD2 + wid*NN;
        #pragma unroll 4
        for (int j = 0; j < NN; ++j)
            acc = fmaf(d2r[j], sY[j*HID + lane], acc);
        sR[wid*HID + lane] = acc;
    }
    __syncthreads();
    if (wid == 0) {
        float s4 = sR[lane] + sR[HID + lane] + sR[2*HID + lane] + sR[3*HID + lane];
        atomicAdd(&P[lane], s4);
    }
    __syncthreads();

    // ---- F: last block: pooled = (P/N)@W2 + b2 ; out = pooled@Wl + bl ----
    if (tid == 0) {
        __threadfence();
        int old = __hip_atomic_fetch_add(cnt, 1, __ATOMIC_ACQ_REL, __HIP_MEMORY_SCOPE_AGENT);
        sLast = (old == 28) ? 1 : 0;
    }
    __syncthreads();
    if (sLast && wid == 0) {
        const float pv = __hip_atomic_load(&P[lane], __ATOMIC_ACQUIRE, __HIP_MEMORY_SCOPE_AGENT);
        const float zbar = pv * (1.0f / NN);
        float q = b2[lane];
        #pragma unroll 8
        for (int j = 0; j < HID; ++j)
            q = fmaf(__shfl(zbar, j, 64), W2[j*HID + lane], q);
        float res[OUTD];
        #pragma unroll
        for (int o = 0; o < OUTD; ++o) {
            float r = q * Wl[lane*OUTD + o];
            #pragma unroll
            for (int off = 32; off > 0; off >>= 1) r += __shfl_xor(r, off, 64);
            res[o] = r;
        }
        if (lane < OUTD) out[lane] = res[lane] + bl[lane];
    }
}

extern "C" void kernel_launch(void* const* d_in, const int* in_sizes, int n_in,
                              void* d_out, int out_size, void* d_ws, size_t ws_size,
                              hipStream_t stream)
{
    const float* enc   = (const float*)d_in[0];
    const float* ea    = (const float*)d_in[1];
    const float* W_enc = (const float*)d_in[3];
    const float* b_enc = (const float*)d_in[4];
    const float* W1    = (const float*)d_in[5];
    const float* b1    = (const float*)d_in[6];
    const float* p1    = (const float*)d_in[7];
    const float* We    = (const float*)d_in[8];
    const float* be    = (const float*)d_in[9];
    const float* pe    = (const float*)d_in[10];
    const float* W2    = (const float*)d_in[11];
    const float* b2    = (const float*)d_in[12];
    const float* p2    = (const float*)d_in[13];
    const float* Wl    = (const float*)d_in[14];
    const float* bl    = (const float*)d_in[15];
    float* ws = (float*)d_ws;

    // Workspace (floats):
    float* Y1 = ws;                 // [NH]
    float* x2 = ws + NH;            // [NH]
    float* d1 = ws + 2*NH;          // [EE]
    float* G  = d1 + EE;            // [EE*EDIM]
    float* dv = G + EE*EDIM;        // [NN]
    float* P  = dv + NN;            // [HID]
    int*  cnt = (int*)(P + HID);    // [1]
    float* out = (float*)d_out;

    kA<<<29 + (EE + 255)/256, 256, 0, stream>>>(enc, ea, W_enc, b_enc, p1, We, W1, Y1, d1, G);
    kB<<<29, 256, 0, stream>>>(d1, Y1, b1, pe, dv, x2, P, cnt);
    kCDEF<<<29, 256, 0, stream>>>(G, dv, x2, be, p2, W2, b2, Wl, bl, P, cnt, out);
}

// Round 12
// 117.416 us; speedup vs baseline: 1.2355x; 1.2355x over previous
//
#include <hip/hip_runtime.h>

// Net_3152505995417: tiny GNN forward (N=116, E=6670, HID=64, EDIM=5).
// R13 = R11 VERBATIM (verified 115.0us best). R12's kC-merge regressed to 145
// (kCDEF=45us: per-wave SERIAL 29-row sweep of scattered G rows at 1 blk/CU
// occupancy -- same latency pathology as R3/R6, gather flavor). Design space
// now bracketed: 4 dispatches = dependency depth (A->B->C->DEF), kernel
// boundary (4.5us) < flag barrier (11) < cg::sync (14); LDS staging beats
// direct-L2 (R10 +18us); parallel kC beats any per-block redundant S.
// Budget: 79us harness-fixed (fill 40 + graph 39) + ~18 dispatch + ~18 walls.
//  kA: nodes: X=enc@W_enc+b (LDS-staged weights), Y1=X@W1; edges: 1 thr/edge
//      d1 + G row.
//  kB: x2=relu(D1@Y1+b1) (LDS-staged), dv=x2.pe; W2 deferred to F.
//  kC: one wave per row i (29 blocks); 5 accumulators, G row loaded once.
//  kDEF: stage x2+S+dv; d2 own 4 rows; Z=D2@x2; pool -> atomicAdd P;
//      last block: pooled=(P/N)@W2+b2, out=pooled@Wl+bl (linear commute).

#define NN   116
#define EE   6670
#define HID  64
#define EDIM 5
#define OUTD 4
#define ENC  122
#define EPSF 1e-10f
#define NH   (NN*HID)   // 7424

__device__ __forceinline__ int eid_ij(int i, int j) {
    int a = i < j ? i : j;
    int b = i < j ? j : i;
    return a*NN - ((a*(a+1)) >> 1) + (b - a - 1);   // triu k=1 row-major
}

// kA: node blocks (0..28): X row = enc@W_enc+b_enc (LDS-staged weights),
//     Y1 row = Xrow@W1. Edge blocks (29..55): one thread per edge: d1 + G row.
__global__ __launch_bounds__(256) void kA(
    const float* __restrict__ enc, const float* __restrict__ ea,
    const float* __restrict__ W_enc, const float* __restrict__ b_enc,
    const float* __restrict__ p1, const float* __restrict__ We,
    const float* __restrict__ W1,
    float* __restrict__ Y1, float* __restrict__ d1, float* __restrict__ G)
{
    const int tid = threadIdx.x;
    if (blockIdx.x < 29) {
        __shared__ __align__(16) float sWe[ENC*HID];   // 31232 B
        __shared__ __align__(16) float sW1[HID*HID];   // 16384 B
        __shared__ __align__(16) float sEnc[4*ENC];    //  1952 B
        __shared__ float sX[4*HID];
        {
            const float4* g4 = (const float4*)W_enc; float4* s4 = (float4*)sWe;
            for (int u = tid; u < ENC*HID/4; u += 256) s4[u] = g4[u];
        }
        {
            const float4* g4 = (const float4*)W1; float4* s4 = (float4*)sW1;
            for (int u = tid; u < HID*HID/4; u += 256) s4[u] = g4[u];
        }
        {
            const float4* g4 = (const float4*)(enc + blockIdx.x*4*ENC); // 1952B-aligned
            float4* s4 = (float4*)sEnc;
            for (int u = tid; u < 4*ENC/4; u += 256) s4[u] = g4[u];
        }
        __syncthreads();
        const int w = tid >> 6, h = tid & 63;
        const int i = blockIdx.x*4 + w;
        float acc = b_enc[h];
        const float* er = sEnc + w*ENC;
        #pragma unroll 4
        for (int k = 0; k < ENC; ++k) acc = fmaf(er[k], sWe[k*HID + h], acc);
        sX[w*HID + h] = acc;
        __syncthreads();
        float a2 = 0.f;
        const float* xr = sX + w*HID;
        #pragma unroll 8
        for (int k = 0; k < HID; ++k) a2 = fmaf(xr[k], sW1[k*HID + h], a2);
        Y1[i*HID + h] = a2;
    } else {
        const int e = (blockIdx.x - 29)*256 + tid;
        if (e < EE) {
            const float* r = ea + e*EDIM;
            float rv[EDIM];
            #pragma unroll
            for (int m = 0; m < EDIM; ++m) rv[m] = r[m];
            float a0 = 0.f;
            #pragma unroll
            for (int k = 0; k < EDIM; ++k) a0 = fmaf(rv[k], p1[k], a0);
            d1[e] = a0;
            #pragma unroll
            for (int k = 0; k < EDIM; ++k) {
                float g = 0.f;
                #pragma unroll
                for (int m = 0; m < EDIM; ++m) g = fmaf(fmaxf(rv[m], 0.f), We[m*EDIM + k], g);
                G[e*EDIM + k] = g;
            }
        }
    }
}

// kB: x2 row = relu(D1@Y1 + b1) (LDS-staged); dv[i] = x2row.pe; write x2.
//     Block 0 zeroes P and cnt.
__global__ __launch_bounds__(256) void kB(
    const float* __restrict__ d1, const float* __restrict__ Y1,
    const float* __restrict__ b1, const float* __restrict__ pe,
    float* __restrict__ dv, float* __restrict__ x2,
    float* __restrict__ P, int* __restrict__ cnt)
{
    __shared__ __align__(16) float sY[NH];   // 29696 B
    __shared__ __align__(16) float sD[EE];   // 26680 B
    const int tid = threadIdx.x;
    if (blockIdx.x == 0) {
        if (tid < HID) P[tid] = 0.f;
        if (tid == 0) *cnt = 0;
    }
    {
        const float4* g4 = (const float4*)Y1; float4* s4 = (float4*)sY;
        for (int u = tid; u < NH/4; u += 256) s4[u] = g4[u];
        const float2* g2 = (const float2*)d1; float2* s2 = (float2*)sD;
        for (int u = tid; u < EE/2; u += 256) s2[u] = g2[u];
    }
    __syncthreads();
    const int w = tid >> 6, h = tid & 63;
    const int i = blockIdx.x*4 + w;
    float acc = b1[h];
    #pragma unroll 4
    for (int j = 0; j < NN; ++j) {
        int jj = (j == i) ? (j ^ 1) : j;
        float wgt = (j == i) ? 0.f : sD[eid_ij(i, jj)];
        acc = fmaf(wgt, sY[jj*HID + h], acc);
    }
    float v = fmaxf(acc, 0.f);
    float r = v * pe[h];
    #pragma unroll
    for (int off = 32; off > 0; off >>= 1) r += __shfl_down(r, off, 64);
    if (h == 0) dv[i] = r;
    x2[i*HID + h] = v;
}

// kC: one wave per row i (29 blocks x 4 waves = 116). Lane j loads the whole
//     G row (5 floats) once, cm once; 5 accumulators; same shfl tree per k.
__global__ __launch_bounds__(256) void kC(
    const float* __restrict__ G, const float* __restrict__ dv,
    float* __restrict__ S)
{
    const int i = blockIdx.x*4 + (threadIdx.x >> 6);    // 0..115
    const int lane = threadIdx.x & 63;
    const float di = dv[i];
    float acc[EDIM] = {0.f, 0.f, 0.f, 0.f, 0.f};
    #pragma unroll
    for (int rep = 0; rep < 2; ++rep) {
        const int j = lane + rep*64;
        if (j < NN && j != i) {
            const float cm = fmaxf(fmaxf(di, dv[j]), 0.f) + EPSF;
            const float* gr = G + eid_ij(i, j)*EDIM;
            #pragma unroll
            for (int k = 0; k < EDIM; ++k) acc[k] += gr[k] / cm;
        }
    }
    #pragma unroll
    for (int k = 0; k < EDIM; ++k) {
        #pragma unroll
        for (int off = 32; off > 0; off >>= 1) acc[k] += __shfl_down(acc[k], off, 64);
    }
    if (lane == 0) {
        #pragma unroll
        for (int k = 0; k < EDIM; ++k) S[i*EDIM + k] = acc[k];
    }
}

// kDEF: per block (29 blocks, 4 rows): stage x2 + S + dv; d2 own rows;
//   Z row = D2@x2; pool Z -> atomicAdd P; last block: pooled=(P/N)@W2+b2,
//   out = pooled@Wl + bl.
__global__ __launch_bounds__(256) void kDEF(
    const float* __restrict__ G, const float* __restrict__ dvg,
    const float* __restrict__ Sg, const float* __restrict__ x2,
    const float* __restrict__ be, const float* __restrict__ p2,
    const float* __restrict__ W2, const float* __restrict__ b2,
    const float* __restrict__ Wl, const float* __restrict__ bl,
    float* __restrict__ P, int* __restrict__ cnt, float* __restrict__ out)
{
    __shared__ __align__(16) float sY[NH];     // x2 tile, 29696 B
    __shared__ float sS[NN*EDIM];
    __shared__ float sDv[NN];
    __shared__ float sD2[4*NN];
    __shared__ float sR[4*HID];
    __shared__ int sLast;
    const int tid = threadIdx.x;
    const int wid = tid >> 6, lane = tid & 63;

    float ber[EDIM], p2r[EDIM];
    #pragma unroll
    for (int k = 0; k < EDIM; ++k) { ber[k] = be[k]; p2r[k] = p2[k]; }

    {
        const float4* g4 = (const float4*)x2; float4* s4 = (float4*)sY;
        for (int u = tid; u < NH/4; u += 256) s4[u] = g4[u];
    }
    for (int u = tid; u < NN*EDIM; u += 256) sS[u] = Sg[u];
    if (tid < NN) sDv[tid] = dvg[tid];
    __syncthreads();

    // ---- D: d2 for the block's own 4 rows (460 edges, G direct) ----
    {
        const int i = blockIdx.x*4 + wid;
        #pragma unroll
        for (int rep = 0; rep < 2; ++rep) {
            const int j = lane + rep*64;
            if (j < NN) {
                float val = 0.f;
                if (j != i) {
                    const int a = i < j ? i : j, b = i < j ? j : i;
                    const int e = a*NN - ((a*(a+1)) >> 1) + (b - a - 1);
                    const float da = sDv[a], db = sDv[b];
                    const float rc = 1.f / (fmaxf(fmaxf(da, db), 0.f) + EPSF);
                    #pragma unroll
                    for (int k = 0; k < EDIM; ++k) {
                        const float gp = G[e*EDIM + k] * rc;
                        const float v = fmaf(da, sS[a*EDIM + k] - gp,
                                       fmaf(db, sS[b*EDIM + k] - gp, ber[k]));
                        val = fmaf(fmaxf(v, 0.f), p2r[k], val);
                    }
                }
                sD2[wid*NN + j] = val;
            }
        }
    }
    __syncthreads();

    // ---- E: Z row = D2@x2 (b2 deferred to F), partial pool ----
    {
        float acc = 0.f;
        const float* d2r = sD2 + wid*NN;
        #pragma unroll 4
        for (int j = 0; j < NN; ++j)
            acc = fmaf(d2r[j], sY[j*HID + lane], acc);
        sR[wid*HID + lane] = acc;
    }
    __syncthreads();
    if (wid == 0) {
        float s4 = sR[lane] + sR[HID + lane] + sR[2*HID + lane] + sR[3*HID + lane];
        atomicAdd(&P[lane], s4);
    }
    __syncthreads();

    // ---- F: last block: pooled = (P/N)@W2 + b2 ; out = pooled@Wl + bl ----
    if (tid == 0) {
        __threadfence();
        int old = __hip_atomic_fetch_add(cnt, 1, __ATOMIC_ACQ_REL, __HIP_MEMORY_SCOPE_AGENT);
        sLast = (old == 28) ? 1 : 0;
    }
    __syncthreads();
    if (sLast && wid == 0) {
        const float pv = __hip_atomic_load(&P[lane], __ATOMIC_ACQUIRE, __HIP_MEMORY_SCOPE_AGENT);
        const float zbar = pv * (1.0f / NN);
        float q = b2[lane];
        #pragma unroll 8
        for (int j = 0; j < HID; ++j)
            q = fmaf(__shfl(zbar, j, 64), W2[j*HID + lane], q);
        float res[OUTD];
        #pragma unroll
        for (int o = 0; o < OUTD; ++o) {
            float r = q * Wl[lane*OUTD + o];
            #pragma unroll
            for (int off = 32; off > 0; off >>= 1) r += __shfl_xor(r, off, 64);
            res[o] = r;
        }
        if (lane < OUTD) out[lane] = res[lane] + bl[lane];
    }
}

extern "C" void kernel_launch(void* const* d_in, const int* in_sizes, int n_in,
                              void* d_out, int out_size, void* d_ws, size_t ws_size,
                              hipStream_t stream)
{
    const float* enc   = (const float*)d_in[0];
    const float* ea    = (const float*)d_in[1];
    const float* W_enc = (const float*)d_in[3];
    const float* b_enc = (const float*)d_in[4];
    const float* W1    = (const float*)d_in[5];
    const float* b1    = (const float*)d_in[6];
    const float* p1    = (const float*)d_in[7];
    const float* We    = (const float*)d_in[8];
    const float* be    = (const float*)d_in[9];
    const float* pe    = (const float*)d_in[10];
    const float* W2    = (const float*)d_in[11];
    const float* b2    = (const float*)d_in[12];
    const float* p2    = (const float*)d_in[13];
    const float* Wl    = (const float*)d_in[14];
    const float* bl    = (const float*)d_in[15];
    float* ws = (float*)d_ws;

    // Workspace (floats):
    float* Y1 = ws;                 // [NH]
    float* x2 = ws + NH;            // [NH]
    float* d1 = ws + 2*NH;          // [EE]
    float* G  = d1 + EE;            // [EE*EDIM]
    float* dv = G + EE*EDIM;        // [NN]
    float* S  = dv + NN;            // [NN*EDIM]
    float* P  = S + NN*EDIM;        // [HID]
    int*  cnt = (int*)(P + HID);    // [1]
    float* out = (float*)d_out;

    kA<<<29 + (EE + 255)/256, 256, 0, stream>>>(enc, ea, W_enc, b_enc, p1, We, W1, Y1, d1, G);
    kB<<<29, 256, 0, stream>>>(d1, Y1, b1, pe, dv, x2, P, cnt);
    kC<<<29, 256, 0, stream>>>(G, dv, S);
    kDEF<<<29, 256, 0, stream>>>(G, dv, S, x2, be, p2, W2, b2, Wl, bl, P, cnt, out);
}